// Round 1
// baseline (252.454 us; speedup 1.0000x reference)
//
#include <hip/hip_runtime.h>

// Problem constants (match reference)
#define BB 8
#define CC 3
#define HH 1024
#define WW 1024
#define NS 15728   // int(1024*1024*0.015)

// Gaussian 5-tap, sigma=1.5, normalized
#define G0 0.1200784f
#define G1 0.2338808f
#define G2 0.2920816f

// ---------------------------------------------------------------------------
// Kernel 1: snow boxes -> per-batch bitmask [B][H][W/32], built per column
// stripe in LDS (no global atomics, no memset needed).
// Grid: (NSTRIPE, B). Each block owns a 64-col stripe (2 words/row, 8 KiB LDS),
// scans all NS spots of its batch, LDS-atomicOrs clipped boxes, writes stripe.
// ---------------------------------------------------------------------------
#define NSTRIPE 16
#define STRW 64

__global__ __launch_bounds__(256) void snow_mask_kernel(
    const int* __restrict__ ys, const int* __restrict__ xs,
    const int* __restrict__ rs, unsigned int* __restrict__ mbits) {
  __shared__ unsigned int lm[HH * 2];
  const int b = blockIdx.y;
  const int sx0 = blockIdx.x * STRW;
  const int tid = threadIdx.x;

  for (int i = tid; i < HH * 2; i += 256) lm[i] = 0u;
  __syncthreads();

  for (int s = tid; s < NS; s += 256) {
    int idx = b * NS + s;
    int y = ys[idx];
    int x = xs[idx];
    int r = rs[idx] + 1;  // radius in {1,2,3}
    int x0 = max(x - r, sx0), x1 = min(x + r, sx0 + (STRW - 1));
    if (x0 > x1) continue;  // box misses this stripe
    int y0 = max(y - r, 0), y1 = min(y + r, HH - 1);
    int lx0 = x0 - sx0, lx1 = x1 - sx0;
    int w0 = lx0 >> 5, w1 = lx1 >> 5;
    unsigned m0 = 0xFFFFFFFFu << (lx0 & 31);
    unsigned m1 = 0xFFFFFFFFu >> (31 - (lx1 & 31));
    if (w0 == w1) {
      unsigned m = m0 & m1;
      for (int py = y0; py <= y1; ++py) atomicOr(&lm[(py << 1) + w0], m);
    } else {
      for (int py = y0; py <= y1; ++py) {
        atomicOr(&lm[(py << 1) + 0], m0);
        atomicOr(&lm[(py << 1) + 1], m1);
      }
    }
  }
  __syncthreads();

  // write stripe: every word of mbits is covered by exactly one block
  unsigned int* dst = mbits + (((unsigned)(b * HH)) << 5) + blockIdx.x * 2;
  for (int i = tid; i < HH * 2; i += 256) {
    dst[((i >> 1) << 5) + (i & 1)] = lm[i];
  }
}

// ---------------------------------------------------------------------------
// Kernel 2: masked-fill (0.95) + separable 5x5 Gaussian + clip, fused.
// LDS-free register sliding window: each thread owns 4 output cols and slides
// down RROWS rows. Per row: 3 aligned float4 loads (cols col-4 / col / col+4)
// + 2 mask words; neighbor lanes share cache lines so L1/L2 absorb overlap.
// One-row-ahead register prefetch; mask combining deferred to consume time.
// Row base addresses are wave-uniform -> SGPR-based loads. No barriers.
// ---------------------------------------------------------------------------
#define RROWS 16

__global__ __launch_bounds__(256, 6) void snow_blur_kernel(
    const float* __restrict__ x, const unsigned int* __restrict__ mbits,
    float* __restrict__ out) {
  const int bz = blockIdx.y;        // b*CC + c
  const int b = bz / CC;
  const int gy0 = blockIdx.x * RROWS;
  const int tid = threadIdx.x;
  const int col = tid << 2;         // output cols col..col+3 (block spans W)

  const float* __restrict__ xp = x + (size_t)bz * (HH * WW);
  const unsigned int* __restrict__ mb = mbits + (((unsigned)(b * HH)) << 5);

  // loop-invariant per-lane geometry
  const int colLc = max(col - 4, 0);
  const int colRc = min(col + 4, WW - 4);
  const unsigned loob16 = (col == 0) ? 16u : 0u;        // left f4 OOB sentinel
  const unsigned roob16 = (col == WW - 4) ? 16u : 0u;   // right f4 OOB sentinel
  const int mwL = colLc >> 5, shL = colLc & 31;
  const int s5 = col & 31;                              // center shift
  const int mwR = colRc >> 5, shR = colRc & 31;

  // issue loads for one row; do NOT touch results (keeps vmcnt un-waited)
  auto loadrow = [&](int gy, float4& A, float4& Bv, float4& Cv,
                     unsigned& wl, unsigned& wr, unsigned& ro) {
    int gyc = min(max(gy, 0), HH - 1);
    ro = (gy != gyc) ? 16u : 0u;   // whole-row OOB -> zero (conv zero padding)
    const float* rp = xp + ((size_t)gyc << 10);
    const unsigned* mrow = mb + (gyc << 5);
    A = *(const float4*)(rp + colLc);
    Bv = *(const float4*)(rp + col);
    Cv = *(const float4*)(rp + colRc);
    wl = mrow[mwL];
    wr = mrow[mwR];
  };

  auto fix4 = [](float4 v, unsigned m) {
    float4 t;
    t.x = (m & 1u) ? 0.95f : v.x;
    t.y = (m & 2u) ? 0.95f : v.y;
    t.z = (m & 4u) ? 0.95f : v.z;
    t.w = (m & 8u) ? 0.95f : v.w;
    if (m & 16u) { t.x = 0.f; t.y = 0.f; t.z = 0.f; t.w = 0.f; }
    return t;
  };

  // consume one staged row -> horizontal 5-tap for 4 cols
  auto hrow = [&](float4 A, float4 Bv, float4 Cv,
                  unsigned wl, unsigned wr, unsigned ro) {
    unsigned wc = (s5 == 0) ? wr : wl;   // center word is one of the two loads
    unsigned ma = ((wl >> shL) & 0xFu) | ro | loob16;
    unsigned mbm = ((wc >> s5) & 0xFu) | ro;
    unsigned mc = ((wr >> shR) & 0xFu) | ro | roob16;
    float4 fA = fix4(A, ma);
    float4 fB = fix4(Bv, mbm);
    float4 fC = fix4(Cv, mc);
    float4 h;
    h.x = G0 * (fA.z + fB.z) + G1 * (fA.w + fB.y) + G2 * fB.x;
    h.y = G0 * (fA.w + fB.w) + G1 * (fB.x + fB.z) + G2 * fB.y;
    h.z = G0 * (fB.x + fC.x) + G1 * (fB.y + fB.w) + G2 * fB.z;
    h.w = G0 * (fB.y + fC.y) + G1 * (fB.z + fC.x) + G2 * fB.w;
    return h;
  };

  // prologue: 4 halo/lead rows -> h window, plus prefetch of first body row
  float4 h0, h1, h2, h3, h4;
  {
    float4 A, Bv, Cv; unsigned wl, wr, ro;
    loadrow(gy0 - 2, A, Bv, Cv, wl, wr, ro); h0 = hrow(A, Bv, Cv, wl, wr, ro);
    loadrow(gy0 - 1, A, Bv, Cv, wl, wr, ro); h1 = hrow(A, Bv, Cv, wl, wr, ro);
    loadrow(gy0 + 0, A, Bv, Cv, wl, wr, ro); h2 = hrow(A, Bv, Cv, wl, wr, ro);
    loadrow(gy0 + 1, A, Bv, Cv, wl, wr, ro); h3 = hrow(A, Bv, Cv, wl, wr, ro);
  }
  float4 cA, cB, cC; unsigned cwl, cwr, cro;
  loadrow(gy0 + 2, cA, cB, cC, cwl, cwr, cro);

  float* op = out + (size_t)bz * (HH * WW) + ((size_t)gy0 << 10) + col;
#pragma unroll
  for (int k = 0; k < RROWS; ++k) {
    // prefetch next row (last iteration's prefetch is dead -> DCE'd)
    float4 nA, nB, nC; unsigned nwl, nwr, nro;
    loadrow(gy0 + k + 3, nA, nB, nC, nwl, nwr, nro);

    h4 = hrow(cA, cB, cC, cwl, cwr, cro);

    float4 s;
    s.x = G0 * (h0.x + h4.x) + G1 * (h1.x + h3.x) + G2 * h2.x;
    s.y = G0 * (h0.y + h4.y) + G1 * (h1.y + h3.y) + G2 * h2.y;
    s.z = G0 * (h0.z + h4.z) + G1 * (h1.z + h3.z) + G2 * h2.z;
    s.w = G0 * (h0.w + h4.w) + G1 * (h1.w + h3.w) + G2 * h2.w;
    s.x = fminf(fmaxf(s.x, 0.f), 1.f);
    s.y = fminf(fmaxf(s.y, 0.f), 1.f);
    s.z = fminf(fmaxf(s.z, 0.f), 1.f);
    s.w = fminf(fmaxf(s.w, 0.f), 1.f);
    *(float4*)op = s;
    op += WW;

    h0 = h1; h1 = h2; h2 = h3; h3 = h4;
    cA = nA; cB = nB; cC = nC; cwl = nwl; cwr = nwr; cro = nro;
  }
}

// ---------------------------------------------------------------------------
extern "C" void kernel_launch(void* const* d_in, const int* in_sizes, int n_in,
                              void* d_out, int out_size, void* d_ws, size_t ws_size,
                              hipStream_t stream) {
  const float* x = (const float*)d_in[0];
  const int* ys = (const int*)d_in[1];
  const int* xs = (const int*)d_in[2];
  const int* rs = (const int*)d_in[3];
  float* out = (float*)d_out;

  unsigned int* mbits = (unsigned int*)d_ws;  // B*H*W/8 = 1 MiB
  // no memset: mask kernel fully overwrites every word of mbits

  dim3 mgrid(NSTRIPE, BB);
  snow_mask_kernel<<<mgrid, 256, 0, stream>>>(ys, xs, rs, mbits);

  dim3 grid(HH / RROWS, BB * CC);
  snow_blur_kernel<<<grid, 256, 0, stream>>>(x, mbits, out);
}

// Round 3
// 205.377 us; speedup vs baseline: 1.2292x; 1.2292x over previous
//
#include <hip/hip_runtime.h>

// Problem constants (match reference)
#define BB 8
#define CC 3
#define HH 1024
#define WW 1024
#define NS 15728        // int(1024*1024*0.015)
#define NG (NS / 4)     // 3932 int4 groups (NS % 4 == 0)

// Gaussian 5-tap, sigma=1.5, normalized
#define G0 0.1200784f
#define G1 0.2338808f
#define G2 0.2920816f

// ---------------------------------------------------------------------------
// Kernel 1: snow boxes -> per-batch bitmask [B][H][W/32], built per 32-col
// stripe in LDS (1 word/row, 4 KiB). 256 blocks (32 stripes x 8 batches) so
// every CU gets work. Spots are scanned as int4 (4 spots per 3 loads) with a
// one-group-ahead prefetch -> the scan is MLP-rich instead of a latency chain.
// No memset needed: every word of mbits is written by exactly one block.
// ---------------------------------------------------------------------------
#define NSTRIPE 32

__global__ __launch_bounds__(256) void snow_mask_kernel(
    const int* __restrict__ ys, const int* __restrict__ xs,
    const int* __restrict__ rs, unsigned int* __restrict__ mbits) {
  __shared__ unsigned int lm[HH];
  const int b = blockIdx.y;
  const int sx0 = blockIdx.x << 5;  // 32-col stripe
  const int tid = threadIdx.x;

  for (int i = tid; i < HH; i += 256) lm[i] = 0u;
  __syncthreads();

  const int4* __restrict__ y4 = (const int4*)(ys + b * NS);
  const int4* __restrict__ x4 = (const int4*)(xs + b * NS);
  const int4* __restrict__ r4 = (const int4*)(rs + b * NS);

  auto spot = [&](int y, int x, int r) {
    r += 1;  // radius in {1,2,3}
    int x0 = max(x - r, sx0), x1 = min(x + r, sx0 + 31);
    if (x0 > x1) return;  // box misses this stripe (~97% reject)
    int y0 = max(y - r, 0), y1 = min(y + r, HH - 1);
    unsigned m = (0xFFFFFFFFu << (x0 & 31)) & (0xFFFFFFFFu >> (31 - (x1 & 31)));
    for (int py = y0; py <= y1; ++py) atomicOr(&lm[py], m);
  };

  int g = tid;
  int4 Y = {0, 0, 0, 0}, X = {0, 0, 0, 0}, R = {0, 0, 0, 0};
  bool have = g < NG;
  if (have) { Y = y4[g]; X = x4[g]; R = r4[g]; }
  while (have) {
    int gn = g + 256;
    int4 Yn = {0, 0, 0, 0}, Xn = {0, 0, 0, 0}, Rn = {0, 0, 0, 0};
    bool haven = gn < NG;
    if (haven) { Yn = y4[gn]; Xn = x4[gn]; Rn = r4[gn]; }  // prefetch
    spot(Y.x, X.x, R.x);
    spot(Y.y, X.y, R.y);
    spot(Y.z, X.z, R.z);
    spot(Y.w, X.w, R.w);
    g = gn; Y = Yn; X = Xn; R = Rn; have = haven;
  }
  __syncthreads();

  unsigned int* dst = mbits + ((unsigned)(b * HH) << 5) + blockIdx.x;
  for (int i = tid; i < HH; i += 256) dst[i << 5] = lm[i];
}

// ---------------------------------------------------------------------------
// Kernel 2: masked-fill (0.95) + separable 5x5 Gaussian + clip, fused.
// Register sliding window, no LDS/barriers. Thread owns 4 cols, slides 16
// rows. Per row: B float4 (own cols) + L/R float2 halo + 2 mask words
// (10 regs). Explicit 3-deep pipeline; the 7-row prologue issues ALL loads
// before any consumption (parallel misses, no serial vmcnt chains). Row-OOB
// flag derived from scalars at consume time. Named Row structs + full unroll
// -> static indexing, registers only.
// ---------------------------------------------------------------------------
#define RROWS 16

struct Row {
  float4 B;      // cols col..col+3
  float2 L;      // cols col-2,col-1 (clamped)
  float2 R;      // cols col+4,col+5 (clamped)
  unsigned m0, m1;
};

__global__ __launch_bounds__(256, 4) void snow_blur_kernel(
    const float* __restrict__ x, const unsigned int* __restrict__ mbits,
    float* __restrict__ out) {
  const int bz = blockIdx.y;        // b*CC + c
  const int b = bz / CC;
  const int gy0 = blockIdx.x * RROWS;
  const int tid = threadIdx.x;
  const int col = tid << 2;         // block spans full row width

  const float* __restrict__ xp = x + (size_t)bz * (HH * WW);
  const unsigned int* __restrict__ mb = mbits + ((unsigned)(b * HH) << 5);

  // loop-invariant per-lane geometry
  const int cL = max(col - 2, 0);
  const int cR = min(col + 4, WW - 2);
  const unsigned loob = (col == 0) ? 16u : 0u;
  const unsigned roob = (col == WW - 4) ? 16u : 0u;
  const int w = cL >> 5;                  // word holding col-2 (clamped)
  const int w2 = min(w + 1, 31);
  const int bpL = cL - (w << 5);          // bit pos of col-2 in 64-bit window
  const int bpB = col - (w << 5);         // bit pos of col   (may be >=32)
  const int bpR = col + 4 - (w << 5);     // bit pos of col+4 (<=36)

  auto loadrow = [&](int gy, Row& rw) {
    int gyc = min(max(gy, 0), HH - 1);
    const float* rp = xp + ((size_t)gyc << 10);
    const unsigned* mrow = mb + (gyc << 5);
    rw.B = *(const float4*)(rp + col);
    rw.L = *(const float2*)(rp + cL);
    rw.R = *(const float2*)(rp + cR);
    rw.m0 = mrow[w];
    rw.m1 = mrow[w2];
  };

  // consume one staged row -> horizontal 5-tap for 4 cols
  auto consume = [&](const Row& rw, unsigned ro) {
    unsigned long long mw =
        (unsigned long long)rw.m0 | ((unsigned long long)rw.m1 << 32);
    unsigned bL = ((unsigned)(mw >> bpL) & 3u) | ro | loob;
    unsigned bB = ((unsigned)(mw >> bpB) & 0xFu) | ro;
    unsigned bR = ((unsigned)(mw >> bpR) & 3u) | ro | roob;
    float2 fL;
    fL.x = (bL & 1u) ? 0.95f : rw.L.x;
    fL.y = (bL & 2u) ? 0.95f : rw.L.y;
    if (bL & 16u) { fL.x = 0.f; fL.y = 0.f; }
    float4 fB;
    fB.x = (bB & 1u) ? 0.95f : rw.B.x;
    fB.y = (bB & 2u) ? 0.95f : rw.B.y;
    fB.z = (bB & 4u) ? 0.95f : rw.B.z;
    fB.w = (bB & 8u) ? 0.95f : rw.B.w;
    if (bB & 16u) { fB.x = 0.f; fB.y = 0.f; fB.z = 0.f; fB.w = 0.f; }
    float2 fR;
    fR.x = (bR & 1u) ? 0.95f : rw.R.x;
    fR.y = (bR & 2u) ? 0.95f : rw.R.y;
    if (bR & 16u) { fR.x = 0.f; fR.y = 0.f; }
    float4 h;
    h.x = G0 * (fL.x + fB.z) + G1 * (fL.y + fB.y) + G2 * fB.x;
    h.y = G0 * (fL.y + fB.w) + G1 * (fB.x + fB.z) + G2 * fB.y;
    h.z = G0 * (fB.x + fR.x) + G1 * (fB.y + fB.w) + G2 * fB.z;
    h.w = G0 * (fB.y + fR.y) + G1 * (fB.z + fR.x) + G2 * fB.w;
    return h;
  };

  auto rof = [&](int gy) { return (gy < 0 || gy >= HH) ? 16u : 0u; };

  // ---- prologue: issue ALL 7 rows' loads before any consumption ----
  Row p0, p1, p2, p3, s0, s1, s2;
  loadrow(gy0 - 2, p0);
  loadrow(gy0 - 1, p1);
  loadrow(gy0 + 0, p2);
  loadrow(gy0 + 1, p3);
  loadrow(gy0 + 2, s0);
  loadrow(gy0 + 3, s1);
  loadrow(gy0 + 4, s2);
  float4 h0 = consume(p0, rof(gy0 - 2));
  float4 h1 = consume(p1, rof(gy0 - 1));
  float4 h2 = consume(p2, 0u);   // gy0..gy0+1 always in range
  float4 h3 = consume(p3, 0u);

  float* op = out + (size_t)bz * (HH * WW) + ((size_t)gy0 << 10) + col;
#pragma unroll
  for (int k = 0; k < RROWS; ++k) {
    Row nr{};
    if (k < RROWS - 3) loadrow(gy0 + 5 + k, nr);   // static guard (unrolled)

    float4 h4 = consume(s0, rof(gy0 + 2 + k));

    float4 s;
    s.x = G0 * (h0.x + h4.x) + G1 * (h1.x + h3.x) + G2 * h2.x;
    s.y = G0 * (h0.y + h4.y) + G1 * (h1.y + h3.y) + G2 * h2.y;
    s.z = G0 * (h0.z + h4.z) + G1 * (h1.z + h3.z) + G2 * h2.z;
    s.w = G0 * (h0.w + h4.w) + G1 * (h1.w + h3.w) + G2 * h2.w;
    s.x = fminf(fmaxf(s.x, 0.f), 1.f);
    s.y = fminf(fmaxf(s.y, 0.f), 1.f);
    s.z = fminf(fmaxf(s.z, 0.f), 1.f);
    s.w = fminf(fmaxf(s.w, 0.f), 1.f);
    *(float4*)op = s;
    op += WW;

    s0 = s1; s1 = s2; s2 = nr;
    h0 = h1; h1 = h2; h2 = h3; h3 = h4;
  }
}

// ---------------------------------------------------------------------------
extern "C" void kernel_launch(void* const* d_in, const int* in_sizes, int n_in,
                              void* d_out, int out_size, void* d_ws, size_t ws_size,
                              hipStream_t stream) {
  const float* x = (const float*)d_in[0];
  const int* ys = (const int*)d_in[1];
  const int* xs = (const int*)d_in[2];
  const int* rs = (const int*)d_in[3];
  float* out = (float*)d_out;

  unsigned int* mbits = (unsigned int*)d_ws;  // B*H*W/8 = 1 MiB
  // no memset: mask kernel fully overwrites every word of mbits

  dim3 mgrid(NSTRIPE, BB);
  snow_mask_kernel<<<mgrid, 256, 0, stream>>>(ys, xs, rs, mbits);

  dim3 grid(HH / RROWS, BB * CC);
  snow_blur_kernel<<<grid, 256, 0, stream>>>(x, mbits, out);
}